// Round 19
// baseline (3447.152 us; speedup 1.0000x reference)
//
#include <hip/hip_runtime.h>
#include <float.h>
#include <math.h>

#define NPT 2048        // points per batch
#define NBATCH 8
#define NPTS_TOTAL 16384
#define KNN 10
#define STAT_BLOCKS 2048   // conv2 row-blocks (163840 rows / 80)
#define NCHUNK 16
#define CHUNKSZ 128     // 2048 / NCHUNK
#define TR 32           // knn candidate tile rows
#define CB 8            // knn channel block

// LDS swizzle: spreads banks for BOTH stride-1 and stride-4 row access.
__device__ __forceinline__ int swz(int r) { return (r ^ (r >> 2)) & 7; }

// ---------------- transpose (S,B,K,D) -> pts[b*2048+n][24] ----------------
__global__ __launch_bounds__(256) void k_pts(const float* __restrict__ x, float* __restrict__ pts) {
    int i = blockIdx.x * 256 + threadIdx.x;
    if (i >= NPTS_TOTAL * 24) return;
    int p = i / 24, c = i - p * 24;
    int b = p >> 11, n = p & 2047;
    pts[i] = x[(n * 8 + b) * 24 + c];
}

// ---------------- prep: f64 norms + transposed f32 copy qT[c][p] ----------------
__global__ __launch_bounds__(256) void k_prep(const float* __restrict__ x, int ld, int C,
                                              double* __restrict__ norms, float* __restrict__ qT) {
    int p = blockIdx.x * 256 + threadIdx.x;
    if (p >= NPTS_TOTAL) return;
    const float* row = x + (size_t)p * ld;
    double s = 0.0;
    for (int c = 0; c < C; ++c) {
        float v = row[c];
        qT[(size_t)c * NPTS_TOTAL + p] = v;
        double dv = (double)v;
        s += dv * dv;
    }
    norms[p] = s;
}

// ---------------- KNN: query-per-thread, chunked candidates, reg top-10 (f64) ----------------
// r18 structure; launch_bounds min-waves REMOVED (test: the "2" attr may cap
// residency at 2 waves/SIMD). Numerics unchanged.
template<int C>
__global__ __launch_bounds__(256) void k_knn2(const float* __restrict__ x, int ld,
                                              const double* __restrict__ norms,
                                              const float* __restrict__ qT,
                                              double* __restrict__ pk, int* __restrict__ pi) {
    __shared__ double tile[TR * C];          // f64 tile (32 KB @ C=128)
    __shared__ double tnorm[TR];
    const int tid = threadIdx.x;
    const int chunk = blockIdx.y;                // chunk on y (XCD-stable groups on x)
    const int p = blockIdx.x * 256 + tid;        // query group on x
    const int b = p >> 11;
    const float* xb = x + (size_t)b * NPT * ld;
    const double* nbase = norms + (size_t)b * NPT;
    const double nn = norms[p];
    const int cand0 = chunk * CHUNKSZ;           // within-batch candidate base

    double keys[10]; int ids[10];
#pragma unroll
    for (int t = 0; t < 10; ++t) { keys[t] = -DBL_MAX; ids[t] = 0; }

    for (int t0 = 0; t0 < CHUNKSZ; t0 += TR) {
        __syncthreads();   // protect previous tile reads
        for (int i = tid; i < TR * C / 4; i += 256) {
            int r = i / (C / 4), c4 = i - r * (C / 4);
            float4 v = ((const float4*)(xb + (size_t)(cand0 + t0 + r) * ld))[c4];
            double* dst = &tile[r * C + c4 * 4];
            dst[0] = (double)v.x;
            dst[1] = (double)v.y;
            dst[2] = (double)v.z;
            dst[3] = (double)v.w;
        }
        if (tid < TR) tnorm[tid] = nbase[cand0 + t0 + tid];
        __syncthreads();

        double acc[TR];
#pragma unroll
        for (int j = 0; j < TR; ++j) acc[j] = 0.0;

        for (int cb = 0; cb < C / CB; ++cb) {
            double qd[CB];
#pragma unroll
            for (int e = 0; e < CB; ++e)
                qd[e] = (double)qT[(size_t)(cb * CB + e) * NPTS_TOTAL + p];
#pragma unroll
            for (int j = 0; j < TR; ++j) {
                const double2 t0v = *(const double2*)&tile[j * C + cb * CB];
                const double2 t1v = *(const double2*)&tile[j * C + cb * CB + 2];
                const double2 t2v = *(const double2*)&tile[j * C + cb * CB + 4];
                const double2 t3v = *(const double2*)&tile[j * C + cb * CB + 6];
                double a = acc[j];
                a = fma(qd[0], t0v.x, a);
                a = fma(qd[1], t0v.y, a);
                a = fma(qd[2], t1v.x, a);
                a = fma(qd[3], t1v.y, a);
                a = fma(qd[4], t2v.x, a);
                a = fma(qd[5], t2v.y, a);
                a = fma(qd[6], t3v.x, a);
                a = fma(qd[7], t3v.y, a);
                acc[j] = a;
            }
        }
#pragma unroll
        for (int j = 0; j < TR; ++j) {
            double d = 2.0 * acc[j] - nn - tnorm[j];
            int m = cand0 + t0 + j;
            if (d > keys[9]) {          // strict >: ascending m => lower-index tie-break
                double cv = d; int ci = m;
#pragma unroll
                for (int t = 0; t < 10; ++t) {
                    bool sw = cv > keys[t];
                    double tk = keys[t]; int ti = ids[t];
                    if (sw) { keys[t] = cv; ids[t] = ci; cv = tk; ci = ti; }
                }
            }
        }
    }
#pragma unroll
    for (int t = 0; t < 10; ++t) {
        pk[((size_t)p * NCHUNK + chunk) * 10 + t] = keys[t];
        pi[((size_t)p * NCHUNK + chunk) * 10 + t] = ids[t];
    }
}

// ---------------- merge NCHUNK sorted 10-lists -> final top-10 ----------------
__global__ __launch_bounds__(256) void k_kmerge(const double* __restrict__ pk,
                                                const int* __restrict__ pi,
                                                int* __restrict__ idx_out) {
    int p = blockIdx.x * 256 + threadIdx.x;
    if (p >= NPTS_TOTAL) return;
    int h[NCHUNK];
#pragma unroll
    for (int c = 0; c < NCHUNK; ++c) h[c] = 0;
    const double* base = pk + (size_t)p * NCHUNK * 10;
    const int* ibase = pi + (size_t)p * NCHUNK * 10;
    for (int t = 0; t < 10; ++t) {
        double bv = -DBL_MAX; int bc = 0;
#pragma unroll
        for (int c = 0; c < NCHUNK; ++c) {
            double v = (h[c] < 10) ? base[c * 10 + h[c]] : -DBL_MAX;
            if (v > bv) { bv = v; bc = c; }   // strict >: ties keep lower chunk (lower idx)
        }
        int sel = 0;
#pragma unroll
        for (int c = 0; c < NCHUNK; ++c) {
            if (c == bc) sel = ibase[c * 10 + h[c]];
            h[c] += (c == bc) ? 1 : 0;
        }
        idx_out[p * 10 + t] = sel;
    }
}

// ---------------- s-GEMM: s[p][o] = sum_c (W2-W1)[o][c] * x[p][c] ----------------
template<int C, int O>
__global__ __launch_bounds__(256, 2) void k_sgemm(const float* __restrict__ x, int ld,
                                                  const float* __restrict__ W,
                                                  float* __restrict__ s) {
    constexpr int C4 = (C / 4 < 8) ? 8 : C / 4;
    __shared__ __align__(16) float smem[(64 + 64) * C4 * 4];
    float4* As = (float4*)smem;
    float4* Bs = (float4*)(smem + 64 * C4 * 4);
    const int tid = threadIdx.x;
    const int p0 = blockIdx.x * 64;
    const int o0 = blockIdx.y * 64;
    for (int i = tid; i < 64 * C4; i += 256) {
        int r = i / C4, c4 = i - r * C4;
        float4 v = make_float4(0.f, 0.f, 0.f, 0.f);
        if (c4 * 4 < C) v = *(const float4*)(x + (size_t)(p0 + r) * ld + c4 * 4);
        As[r * C4 + (c4 ^ swz(r))] = v;
    }
    for (int i = tid; i < 64 * C4; i += 256) {
        int oo = i / C4, c4 = i - oo * C4;
        float4 v = make_float4(0.f, 0.f, 0.f, 0.f);
        if (c4 * 4 < C) {
            const float* wr = W + (size_t)(o0 + oo) * 2 * C;
            float4 w1 = *(const float4*)(wr + c4 * 4);
            float4 w2 = *(const float4*)(wr + C + c4 * 4);
            v = make_float4(w2.x - w1.x, w2.y - w1.y, w2.z - w1.z, w2.w - w1.w);
        }
        Bs[oo * C4 + (c4 ^ swz(oo))] = v;
    }
    __syncthreads();
    const int tx = tid & 15, ty = tid >> 4;
    float acc[4][4];
#pragma unroll
    for (int a = 0; a < 4; ++a)
#pragma unroll
        for (int b = 0; b < 4; ++b) acc[a][b] = 0.f;
    for (int c4 = 0; c4 < C4; ++c4) {
        float4 av[4], bv[4];
#pragma unroll
        for (int rj = 0; rj < 4; ++rj) { int r = ty * 4 + rj; av[rj] = As[r * C4 + (c4 ^ swz(r))]; }
#pragma unroll
        for (int oj = 0; oj < 4; ++oj) { int oo = tx * 4 + oj; bv[oj] = Bs[oo * C4 + (c4 ^ swz(oo))]; }
#pragma unroll
        for (int rj = 0; rj < 4; ++rj)
#pragma unroll
            for (int oj = 0; oj < 4; ++oj) {
                acc[rj][oj] = fmaf(av[rj].x, bv[oj].x, acc[rj][oj]);
                acc[rj][oj] = fmaf(av[rj].y, bv[oj].y, acc[rj][oj]);
                acc[rj][oj] = fmaf(av[rj].z, bv[oj].z, acc[rj][oj]);
                acc[rj][oj] = fmaf(av[rj].w, bv[oj].w, acc[rj][oj]);
            }
    }
#pragma unroll
    for (int rj = 0; rj < 4; ++rj) {
        float4 v = make_float4(acc[rj][0], acc[rj][1], acc[rj][2], acc[rj][3]);
        *(float4*)(s + (size_t)(p0 + ty * 4 + rj) * O + o0 + tx * 4) = v;
    }
}

// ---------------- edgeconv GEMM: tile 80 gathered rows x 64 o ----------------
template<int PASS, int C, int O>
__global__ __launch_bounds__(256, 2) void k_conv2(const float* __restrict__ x, int ld,
                                                  const int* __restrict__ idx,
                                                  const float* __restrict__ W,
                                                  const float* __restrict__ sbuf,
                                                  double* __restrict__ partials,
                                                  const float* __restrict__ ss,
                                                  float* __restrict__ out, int ldo) {
    constexpr int C4 = (C / 4 < 8) ? 8 : C / 4;
    __shared__ __align__(16) float smem[(80 + 64) * C4 * 4];
    __shared__ int sidx[80];
    float4* As = (float4*)smem;
    float4* Bs = (float4*)(smem + 80 * C4 * 4);

    const int tid = threadIdx.x;
    const int rb = blockIdx.x;            // 0..2047
    const int o0 = blockIdx.y * 64;
    const int p0 = rb * 8;                // 8 points per block (same batch: 8 | 2048)
    const int b = p0 >> 11;
    const float* xb = x + (size_t)b * NPT * ld;

    if (tid < 80) sidx[tid] = idx[p0 * KNN + tid];
    __syncthreads();

    for (int i = tid; i < 80 * C4; i += 256) {
        int r = i / C4, c4 = i - r * C4;
        float4 v = make_float4(0.f, 0.f, 0.f, 0.f);
        if (c4 * 4 < C) v = *(const float4*)(xb + (size_t)sidx[r] * ld + c4 * 4);
        As[r * C4 + (c4 ^ swz(r))] = v;
    }
    for (int i = tid; i < 64 * C4; i += 256) {
        int oo = i / C4, c4 = i - oo * C4;
        float4 v = make_float4(0.f, 0.f, 0.f, 0.f);
        if (c4 * 4 < C) v = *(const float4*)(W + (size_t)(o0 + oo) * 2 * C + c4 * 4);
        Bs[oo * C4 + (c4 ^ swz(oo))] = v;
    }
    __syncthreads();

    const int tx = tid & 15, ty = tid >> 4;
    const int o_l = tx * 4;
    float acc[5][4];
#pragma unroll
    for (int a = 0; a < 5; ++a)
#pragma unroll
        for (int c = 0; c < 4; ++c) acc[a][c] = 0.f;

    for (int c4 = 0; c4 < C4; ++c4) {
        float4 av[5], bv[4];
#pragma unroll
        for (int rj = 0; rj < 5; ++rj) { int r = ty * 5 + rj; av[rj] = As[r * C4 + (c4 ^ swz(r))]; }
#pragma unroll
        for (int oj = 0; oj < 4; ++oj) { int oo = o_l + oj; bv[oj] = Bs[oo * C4 + (c4 ^ swz(oo))]; }
#pragma unroll
        for (int rj = 0; rj < 5; ++rj)
#pragma unroll
            for (int oj = 0; oj < 4; ++oj) {
                acc[rj][oj] = fmaf(av[rj].x, bv[oj].x, acc[rj][oj]);
                acc[rj][oj] = fmaf(av[rj].y, bv[oj].y, acc[rj][oj]);
                acc[rj][oj] = fmaf(av[rj].z, bv[oj].z, acc[rj][oj]);
                acc[rj][oj] = fmaf(av[rj].w, bv[oj].w, acc[rj][oj]);
            }
    }

    // rows ty*5..ty*5+4 all belong to point pt = ty>>1 (k 0-4 for even ty, 5-9 odd)
    const int pt = ty >> 1;
    const float4 s4 = *(const float4*)(sbuf + (size_t)(p0 + pt) * O + o0 + o_l);
    const float* s4f = (const float*)&s4;

    if (PASS == 0) {
        double sum[4] = {0, 0, 0, 0}, sq[4] = {0, 0, 0, 0};
#pragma unroll
        for (int rj = 0; rj < 5; ++rj)
#pragma unroll
            for (int oj = 0; oj < 4; ++oj) {
                float hf = acc[rj][oj] + s4f[oj];
                double hd = (double)hf;
                sum[oj] += hd; sq[oj] += hd * hd;
            }
        __syncthreads();
        double* red = (double*)smem;   // [16][64][2] = 16 KB
#pragma unroll
        for (int oj = 0; oj < 4; ++oj) {
            red[(ty * 64 + o_l + oj) * 2 + 0] = sum[oj];
            red[(ty * 64 + o_l + oj) * 2 + 1] = sq[oj];
        }
        __syncthreads();
        if (tid < 128) {
            int o = tid & 63, w = tid >> 6;
            double a = 0.0;
            for (int t2 = 0; t2 < 16; ++t2) a += red[(t2 * 64 + o) * 2 + w];
            partials[(size_t)rb * 2 * O + (size_t)w * O + o0 + o] = a;
        }
    } else {
        float m4[4];
#pragma unroll
        for (int oj = 0; oj < 4; ++oj) {
            float sc = ss[o0 + o_l + oj], sh = ss[O + o0 + o_l + oj];
            float m = -FLT_MAX;
#pragma unroll
            for (int rj = 0; rj < 5; ++rj) {
                float h = (acc[rj][oj] + s4f[oj]) * sc + sh;
                h = h > 0.f ? h : 0.2f * h;
                m = fmaxf(m, h);
            }
            m4[oj] = m;
        }
        __syncthreads();
        float* red = smem;             // [16][64]
#pragma unroll
        for (int oj = 0; oj < 4; ++oj) red[ty * 64 + o_l + oj] = m4[oj];
        __syncthreads();
        if ((ty & 1) == 0) {
            float4 o4;
            float* po = (float*)&o4;
#pragma unroll
            for (int oj = 0; oj < 4; ++oj)
                po[oj] = fmaxf(red[ty * 64 + o_l + oj], red[(ty + 1) * 64 + o_l + oj]);
            *(float4*)(out + (size_t)(p0 + pt) * ldo + o0 + o_l) = o4;
        }
    }
}

// ---------------- BN finalize: deterministic fixed-order reduction ----------------
__global__ __launch_bounds__(256) void k_bnstats(const double* __restrict__ partials,
                                                 const float* __restrict__ g,
                                                 const float* __restrict__ be,
                                                 float* __restrict__ ss, int O) {
    int o = threadIdx.x;
    if (o >= O) return;
    double sum = 0.0, sq = 0.0;
    for (int b = 0; b < STAT_BLOCKS; ++b) {
        sum += partials[(size_t)b * 2 * O + o];
        sq  += partials[(size_t)b * 2 * O + O + o];
    }
    const double M = 163840.0;   // 8*2048*10
    double mu = sum / M;
    double var = sq / M - mu * mu;
    if (var < 0.0) var = 0.0;
    float scv = (float)((double)g[o] / sqrt(var + 1e-5));
    ss[o] = scv;
    ss[O + o] = be[o] - (float)mu * scv;
}

// ---------------- dense GEMM: 64x64 tile, BK=64, 4x4 acc/thread ----------------
template<int ACT>
__global__ __launch_bounds__(256, 2) void k_dense2(const float* __restrict__ in, int ldi, int Cin,
                                                   const float* __restrict__ W,
                                                   const float* __restrict__ bias,
                                                   float* __restrict__ out, int ldo, int Cout) {
    __shared__ __align__(16) float smem[2 * 64 * 64];   // As + Bs, 32 KB
    float4* As = (float4*)smem;
    float4* Bs = (float4*)(smem + 64 * 64);
    const int tid = threadIdx.x;
    const int p0 = blockIdx.x * 64;
    const int o0 = blockIdx.y * 64;
    const int tx = tid & 15, ty = tid >> 4;

    float acc[4][4];
#pragma unroll
    for (int a = 0; a < 4; ++a)
#pragma unroll
        for (int b = 0; b < 4; ++b) acc[a][b] = 0.f;

    const int ntile = (Cin + 63) / 64;
    for (int kt = 0; kt < ntile; ++kt) {
        const int c0 = kt * 64;
        __syncthreads();   // protect previous tile reads
        for (int i = tid; i < 64 * 16; i += 256) {
            int r = i >> 4, c4 = i & 15;
            float4 v = make_float4(0.f, 0.f, 0.f, 0.f);
            if (c0 + c4 * 4 < Cin) v = *(const float4*)(in + (size_t)(p0 + r) * ldi + c0 + c4 * 4);
            As[r * 16 + (c4 ^ swz(r))] = v;
        }
        for (int i = tid; i < 64 * 16; i += 256) {
            int oo = i >> 4, c4 = i & 15;
            float4 v = make_float4(0.f, 0.f, 0.f, 0.f);
            if (o0 + oo < Cout && c0 + c4 * 4 < Cin)
                v = *(const float4*)(W + (size_t)(o0 + oo) * Cin + c0 + c4 * 4);
            Bs[oo * 16 + (c4 ^ swz(oo))] = v;
        }
        __syncthreads();
#pragma unroll
        for (int c4 = 0; c4 < 16; ++c4) {
            float4 av[4], bv[4];
#pragma unroll
            for (int rj = 0; rj < 4; ++rj) { int r = ty * 4 + rj; av[rj] = As[r * 16 + (c4 ^ swz(r))]; }
#pragma unroll
            for (int oj = 0; oj < 4; ++oj) { int oo = tx * 4 + oj; bv[oj] = Bs[oo * 16 + (c4 ^ swz(oo))]; }
#pragma unroll
            for (int rj = 0; rj < 4; ++rj)
#pragma unroll
                for (int oj = 0; oj < 4; ++oj) {
                    acc[rj][oj] = fmaf(av[rj].x, bv[oj].x, acc[rj][oj]);
                    acc[rj][oj] = fmaf(av[rj].y, bv[oj].y, acc[rj][oj]);
                    acc[rj][oj] = fmaf(av[rj].z, bv[oj].z, acc[rj][oj]);
                    acc[rj][oj] = fmaf(av[rj].w, bv[oj].w, acc[rj][oj]);
                }
        }
    }

    const int ob = o0 + tx * 4;
    float bv4[4] = {0.f, 0.f, 0.f, 0.f};
    if (bias) {
#pragma unroll
        for (int oj = 0; oj < 4; ++oj) if (ob + oj < Cout) bv4[oj] = bias[ob + oj];
    }
#pragma unroll
    for (int rj = 0; rj < 4; ++rj) {
        float v4[4];
#pragma unroll
        for (int oj = 0; oj < 4; ++oj) {
            float v = acc[rj][oj] + bv4[oj];
            if (ACT) v = v > 0.f ? v : 0.2f * v;
            v4[oj] = v;
        }
        float* orow = out + (size_t)(p0 + ty * 4 + rj) * ldo;
        if (ob + 3 < Cout) {
            *(float4*)(orow + ob) = make_float4(v4[0], v4[1], v4[2], v4[3]);
        } else {
#pragma unroll
            for (int oj = 0; oj < 4; ++oj) if (ob + oj < Cout) orow[ob + oj] = v4[oj];
        }
    }
}

extern "C" void kernel_launch(void* const* d_in, const int* in_sizes, int n_in,
                              void* d_out, int out_size, void* d_ws, size_t ws_size,
                              hipStream_t stream) {
    const float* x   = (const float*)d_in[0];
    const float* W1  = (const float*)d_in[1];
    const float* g1  = (const float*)d_in[2];
    const float* b1  = (const float*)d_in[3];
    const float* W2  = (const float*)d_in[4];
    const float* g2  = (const float*)d_in[5];
    const float* b2  = (const float*)d_in[6];
    const float* W3  = (const float*)d_in[7];
    const float* g3  = (const float*)d_in[8];
    const float* b3  = (const float*)d_in[9];
    const float* W4  = (const float*)d_in[10];
    const float* g4  = (const float*)d_in[11];
    const float* b4  = (const float*)d_in[12];
    const float* W5  = (const float*)d_in[13];
    const float* W6  = (const float*)d_in[14];
    const float* Wd1 = (const float*)d_in[15];
    const float* bd1 = (const float*)d_in[16];
    const float* Wd2 = (const float*)d_in[17];
    const float* bd2 = (const float*)d_in[18];

    char* ws = (char*)d_ws;
    float* cat    = (float*)(ws);                 // [0, 33,554,432)
    double* norms = (double*)(ws + 33554432);     // 131,072 B (knn phase)
    float* qT     = (float*)(ws + 33685504);      // 8,388,608 B (knn phase)
    float* pts    = (float*)(ws + 57802752);      // 1,572,864 B (layer-1 input)
    int*   idx    = (int*)  (ws + 59375616);      // 655,360 B
    float* ssb    = (float*)(ws + 60030976);      // 4,096 B
    float* sbuf   = (float*)(ws + 33685504);      // <=16.8 MB, overlays qT (conv phase)
    double* parts = (double*)(ws + 50462720);     // <=8.4 MB, overlays pts at L4 only (pts dead)
    float* h5     = (float*)(ws + 33554432);      // tail only
    float* tmp    = (float*)(ws);                 // tail only, overlays dead cat

    float* feat = (float*)d_out;                // 16384 x 552
    float* logi = (float*)d_out + 9043968;      // 16384 x 255
    // knn-phase scratch in d_out (52.9 MB; fully rewritten by the tail):
    double* pk  = (double*)d_out;                       // 16384*16*10 f64 = 20,971,520 B
    int*    pi  = (int*)((char*)d_out + 20971520);      // 10,485,760 B

    dim3 blk(256);
    dim3 kgrid(64, NCHUNK);   // x = query group (XCD-stable), y = chunk

    k_pts<<<dim3((NPTS_TOTAL * 24 + 255) / 256), blk, 0, stream>>>(x, pts);

    // ---- layer 1: C=24, O=64 ----
    k_prep<<<dim3(64), blk, 0, stream>>>(pts, 24, 24, norms, qT);
    k_knn2<24><<<kgrid, blk, 0, stream>>>(pts, 24, norms, qT, pk, pi);
    k_kmerge<<<dim3(64), blk, 0, stream>>>(pk, pi, idx);
    k_sgemm<24, 64><<<dim3(256, 1), blk, 0, stream>>>(pts, 24, W1, sbuf);
    k_conv2<0, 24, 64><<<dim3(STAT_BLOCKS, 1), blk, 0, stream>>>(pts, 24, idx, W1, sbuf, parts, nullptr, nullptr, 0);
    k_bnstats<<<dim3(1), blk, 0, stream>>>(parts, g1, b1, ssb, 64);
    k_conv2<1, 24, 64><<<dim3(STAT_BLOCKS, 1), blk, 0, stream>>>(pts, 24, idx, W1, sbuf, nullptr, ssb, cat + 0, 512);

    // ---- layer 2: C=64, O=64 ----
    k_prep<<<dim3(64), blk, 0, stream>>>(cat + 0, 512, 64, norms, qT);
    k_knn2<64><<<kgrid, blk, 0, stream>>>(cat + 0, 512, norms, qT, pk, pi);
    k_kmerge<<<dim3(64), blk, 0, stream>>>(pk, pi, idx);
    k_sgemm<64, 64><<<dim3(256, 1), blk, 0, stream>>>(cat + 0, 512, W2, sbuf);
    k_conv2<0, 64, 64><<<dim3(STAT_BLOCKS, 1), blk, 0, stream>>>(cat + 0, 512, idx, W2, sbuf, parts, nullptr, nullptr, 0);
    k_bnstats<<<dim3(1), blk, 0, stream>>>(parts, g2, b2, ssb, 64);
    k_conv2<1, 64, 64><<<dim3(STAT_BLOCKS, 1), blk, 0, stream>>>(cat + 0, 512, idx, W2, sbuf, nullptr, ssb, cat + 64, 512);

    // ---- layer 3: C=64, O=128 ----
    k_prep<<<dim3(64), blk, 0, stream>>>(cat + 64, 512, 64, norms, qT);
    k_knn2<64><<<kgrid, blk, 0, stream>>>(cat + 64, 512, norms, qT, pk, pi);
    k_kmerge<<<dim3(64), blk, 0, stream>>>(pk, pi, idx);
    k_sgemm<64, 128><<<dim3(256, 2), blk, 0, stream>>>(cat + 64, 512, W3, sbuf);
    k_conv2<0, 64, 128><<<dim3(STAT_BLOCKS, 2), blk, 0, stream>>>(cat + 64, 512, idx, W3, sbuf, parts, nullptr, nullptr, 0);
    k_bnstats<<<dim3(1), blk, 0, stream>>>(parts, g3, b3, ssb, 128);
    k_conv2<1, 64, 128><<<dim3(STAT_BLOCKS, 2), blk, 0, stream>>>(cat + 64, 512, idx, W3, sbuf, nullptr, ssb, cat + 128, 512);

    // ---- layer 4: C=128, O=256 ----
    k_prep<<<dim3(64), blk, 0, stream>>>(cat + 128, 512, 128, norms, qT);
    k_knn2<128><<<kgrid, blk, 0, stream>>>(cat + 128, 512, norms, qT, pk, pi);
    k_kmerge<<<dim3(64), blk, 0, stream>>>(pk, pi, idx);
    k_sgemm<128, 256><<<dim3(256, 4), blk, 0, stream>>>(cat + 128, 512, W4, sbuf);
    k_conv2<0, 128, 256><<<dim3(STAT_BLOCKS, 4), blk, 0, stream>>>(cat + 128, 512, idx, W4, sbuf, parts, nullptr, nullptr, 0);
    k_bnstats<<<dim3(1), blk, 0, stream>>>(parts, g4, b4, ssb, 256);
    k_conv2<1, 128, 256><<<dim3(STAT_BLOCKS, 4), blk, 0, stream>>>(cat + 128, 512, idx, W4, sbuf, nullptr, ssb, cat + 256, 512);

    // ---- tail: register-blocked GEMMs (fully rewrite d_out: feat then logi) ----
    k_dense2<1><<<dim3(256, 4), blk, 0, stream>>>(cat, 512, 512, W5, nullptr, h5, 256, 256);
    k_dense2<1><<<dim3(256, 9), blk, 0, stream>>>(h5, 256, 256, W6, nullptr, feat, 552, 552);
    k_dense2<0><<<dim3(256, 9), blk, 0, stream>>>(feat, 552, 552, Wd1, bd1, tmp, 552, 552);
    k_dense2<0><<<dim3(256, 4), blk, 0, stream>>>(tmp, 552, 552, Wd2, bd2, logi, 255, 255);
}

// Round 20
// 3091.118 us; speedup vs baseline: 1.1152x; 1.1152x over previous
//
#include <hip/hip_runtime.h>
#include <float.h>
#include <math.h>

#define NPT 2048        // points per batch
#define NBATCH 8
#define NPTS_TOTAL 16384
#define KNN 10
#define STAT_BLOCKS 2048   // conv2 row-blocks (163840 rows / 80)
#define NCHUNK 8
#define CHUNKSZ 256     // 2048 / NCHUNK
#define TR 32           // knn candidate tile rows
#define CB 8            // knn channel block

// LDS swizzle: spreads banks for BOTH stride-1 and stride-4 row access.
__device__ __forceinline__ int swz(int r) { return (r ^ (r >> 2)) & 7; }

// ---------------- transpose (S,B,K,D) -> pts[b*2048+n][24] ----------------
__global__ __launch_bounds__(256) void k_pts(const float* __restrict__ x, float* __restrict__ pts) {
    int i = blockIdx.x * 256 + threadIdx.x;
    if (i >= NPTS_TOTAL * 24) return;
    int p = i / 24, c = i - p * 24;
    int b = p >> 11, n = p & 2047;
    pts[i] = x[(n * 8 + b) * 24 + c];
}

// ---------------- prep: f64 norms + transposed f32 copy qT[c][p] ----------------
__global__ __launch_bounds__(256) void k_prep(const float* __restrict__ x, int ld, int C,
                                              double* __restrict__ norms, float* __restrict__ qT) {
    int p = blockIdx.x * 256 + threadIdx.x;
    if (p >= NPTS_TOTAL) return;
    const float* row = x + (size_t)p * ld;
    double s = 0.0;
    for (int c = 0; c < C; ++c) {
        float v = row[c];
        qT[(size_t)c * NPTS_TOTAL + p] = v;
        double dv = (double)v;
        s += dv * dv;
    }
    norms[p] = s;
}

// ---------------- KNN: query-per-thread, chunked candidates, reg top-10 (f64) ----------------
// Best-known config (round 17, 3091 us): f64 LDS tile (cvt once at staging, exact),
// XCD-stable grid (qgroup on x, chunk on y -> one group's chunk-blocks share an XCD L2),
// NCHUNK=8, launch_bounds(256,2).
template<int C>
__global__ __launch_bounds__(256, 2) void k_knn2(const float* __restrict__ x, int ld,
                                                 const double* __restrict__ norms,
                                                 const float* __restrict__ qT,
                                                 double* __restrict__ pk, int* __restrict__ pi) {
    __shared__ double tile[TR * C];          // f64 tile (32 KB @ C=128)
    __shared__ double tnorm[TR];
    const int tid = threadIdx.x;
    const int chunk = blockIdx.y;                // chunk on y (XCD-stable groups on x)
    const int p = blockIdx.x * 256 + tid;        // query group on x
    const int b = p >> 11;
    const float* xb = x + (size_t)b * NPT * ld;
    const double* nbase = norms + (size_t)b * NPT;
    const double nn = norms[p];
    const int cand0 = chunk * CHUNKSZ;           // within-batch candidate base

    double keys[10]; int ids[10];
#pragma unroll
    for (int t = 0; t < 10; ++t) { keys[t] = -DBL_MAX; ids[t] = 0; }

    for (int t0 = 0; t0 < CHUNKSZ; t0 += TR) {
        __syncthreads();   // protect previous tile reads
        for (int i = tid; i < TR * C / 4; i += 256) {
            int r = i / (C / 4), c4 = i - r * (C / 4);
            float4 v = ((const float4*)(xb + (size_t)(cand0 + t0 + r) * ld))[c4];
            double* dst = &tile[r * C + c4 * 4];
            dst[0] = (double)v.x;
            dst[1] = (double)v.y;
            dst[2] = (double)v.z;
            dst[3] = (double)v.w;
        }
        if (tid < TR) tnorm[tid] = nbase[cand0 + t0 + tid];
        __syncthreads();

        double acc[TR];
#pragma unroll
        for (int j = 0; j < TR; ++j) acc[j] = 0.0;

        for (int cb = 0; cb < C / CB; ++cb) {
            double qd[CB];
#pragma unroll
            for (int e = 0; e < CB; ++e)
                qd[e] = (double)qT[(size_t)(cb * CB + e) * NPTS_TOTAL + p];
#pragma unroll
            for (int j = 0; j < TR; ++j) {
                const double2 t0v = *(const double2*)&tile[j * C + cb * CB];
                const double2 t1v = *(const double2*)&tile[j * C + cb * CB + 2];
                const double2 t2v = *(const double2*)&tile[j * C + cb * CB + 4];
                const double2 t3v = *(const double2*)&tile[j * C + cb * CB + 6];
                double a = acc[j];
                a = fma(qd[0], t0v.x, a);
                a = fma(qd[1], t0v.y, a);
                a = fma(qd[2], t1v.x, a);
                a = fma(qd[3], t1v.y, a);
                a = fma(qd[4], t2v.x, a);
                a = fma(qd[5], t2v.y, a);
                a = fma(qd[6], t3v.x, a);
                a = fma(qd[7], t3v.y, a);
                acc[j] = a;
            }
        }
#pragma unroll
        for (int j = 0; j < TR; ++j) {
            double d = 2.0 * acc[j] - nn - tnorm[j];
            int m = cand0 + t0 + j;
            if (d > keys[9]) {          // strict >: ascending m => lower-index tie-break
                double cv = d; int ci = m;
#pragma unroll
                for (int t = 0; t < 10; ++t) {
                    bool sw = cv > keys[t];
                    double tk = keys[t]; int ti = ids[t];
                    if (sw) { keys[t] = cv; ids[t] = ci; cv = tk; ci = ti; }
                }
            }
        }
    }
#pragma unroll
    for (int t = 0; t < 10; ++t) {
        pk[((size_t)p * NCHUNK + chunk) * 10 + t] = keys[t];
        pi[((size_t)p * NCHUNK + chunk) * 10 + t] = ids[t];
    }
}

// ---------------- merge NCHUNK sorted 10-lists -> final top-10 ----------------
__global__ __launch_bounds__(256) void k_kmerge(const double* __restrict__ pk,
                                                const int* __restrict__ pi,
                                                int* __restrict__ idx_out) {
    int p = blockIdx.x * 256 + threadIdx.x;
    if (p >= NPTS_TOTAL) return;
    int h[NCHUNK];
#pragma unroll
    for (int c = 0; c < NCHUNK; ++c) h[c] = 0;
    const double* base = pk + (size_t)p * NCHUNK * 10;
    const int* ibase = pi + (size_t)p * NCHUNK * 10;
    for (int t = 0; t < 10; ++t) {
        double bv = -DBL_MAX; int bc = 0;
#pragma unroll
        for (int c = 0; c < NCHUNK; ++c) {
            double v = (h[c] < 10) ? base[c * 10 + h[c]] : -DBL_MAX;
            if (v > bv) { bv = v; bc = c; }   // strict >: ties keep lower chunk (lower idx)
        }
        int sel = 0;
#pragma unroll
        for (int c = 0; c < NCHUNK; ++c) {
            if (c == bc) sel = ibase[c * 10 + h[c]];
            h[c] += (c == bc) ? 1 : 0;
        }
        idx_out[p * 10 + t] = sel;
    }
}

// ---------------- s-GEMM: s[p][o] = sum_c (W2-W1)[o][c] * x[p][c] ----------------
template<int C, int O>
__global__ __launch_bounds__(256, 2) void k_sgemm(const float* __restrict__ x, int ld,
                                                  const float* __restrict__ W,
                                                  float* __restrict__ s) {
    constexpr int C4 = (C / 4 < 8) ? 8 : C / 4;
    __shared__ __align__(16) float smem[(64 + 64) * C4 * 4];
    float4* As = (float4*)smem;
    float4* Bs = (float4*)(smem + 64 * C4 * 4);
    const int tid = threadIdx.x;
    const int p0 = blockIdx.x * 64;
    const int o0 = blockIdx.y * 64;
    for (int i = tid; i < 64 * C4; i += 256) {
        int r = i / C4, c4 = i - r * C4;
        float4 v = make_float4(0.f, 0.f, 0.f, 0.f);
        if (c4 * 4 < C) v = *(const float4*)(x + (size_t)(p0 + r) * ld + c4 * 4);
        As[r * C4 + (c4 ^ swz(r))] = v;
    }
    for (int i = tid; i < 64 * C4; i += 256) {
        int oo = i / C4, c4 = i - oo * C4;
        float4 v = make_float4(0.f, 0.f, 0.f, 0.f);
        if (c4 * 4 < C) {
            const float* wr = W + (size_t)(o0 + oo) * 2 * C;
            float4 w1 = *(const float4*)(wr + c4 * 4);
            float4 w2 = *(const float4*)(wr + C + c4 * 4);
            v = make_float4(w2.x - w1.x, w2.y - w1.y, w2.z - w1.z, w2.w - w1.w);
        }
        Bs[oo * C4 + (c4 ^ swz(oo))] = v;
    }
    __syncthreads();
    const int tx = tid & 15, ty = tid >> 4;
    float acc[4][4];
#pragma unroll
    for (int a = 0; a < 4; ++a)
#pragma unroll
        for (int b = 0; b < 4; ++b) acc[a][b] = 0.f;
    for (int c4 = 0; c4 < C4; ++c4) {
        float4 av[4], bv[4];
#pragma unroll
        for (int rj = 0; rj < 4; ++rj) { int r = ty * 4 + rj; av[rj] = As[r * C4 + (c4 ^ swz(r))]; }
#pragma unroll
        for (int oj = 0; oj < 4; ++oj) { int oo = tx * 4 + oj; bv[oj] = Bs[oo * C4 + (c4 ^ swz(oo))]; }
#pragma unroll
        for (int rj = 0; rj < 4; ++rj)
#pragma unroll
            for (int oj = 0; oj < 4; ++oj) {
                acc[rj][oj] = fmaf(av[rj].x, bv[oj].x, acc[rj][oj]);
                acc[rj][oj] = fmaf(av[rj].y, bv[oj].y, acc[rj][oj]);
                acc[rj][oj] = fmaf(av[rj].z, bv[oj].z, acc[rj][oj]);
                acc[rj][oj] = fmaf(av[rj].w, bv[oj].w, acc[rj][oj]);
            }
    }
#pragma unroll
    for (int rj = 0; rj < 4; ++rj) {
        float4 v = make_float4(acc[rj][0], acc[rj][1], acc[rj][2], acc[rj][3]);
        *(float4*)(s + (size_t)(p0 + ty * 4 + rj) * O + o0 + tx * 4) = v;
    }
}

// ---------------- edgeconv GEMM: tile 80 gathered rows x 64 o ----------------
template<int PASS, int C, int O>
__global__ __launch_bounds__(256, 2) void k_conv2(const float* __restrict__ x, int ld,
                                                  const int* __restrict__ idx,
                                                  const float* __restrict__ W,
                                                  const float* __restrict__ sbuf,
                                                  double* __restrict__ partials,
                                                  const float* __restrict__ ss,
                                                  float* __restrict__ out, int ldo) {
    constexpr int C4 = (C / 4 < 8) ? 8 : C / 4;
    __shared__ __align__(16) float smem[(80 + 64) * C4 * 4];
    __shared__ int sidx[80];
    float4* As = (float4*)smem;
    float4* Bs = (float4*)(smem + 80 * C4 * 4);

    const int tid = threadIdx.x;
    const int rb = blockIdx.x;            // 0..2047
    const int o0 = blockIdx.y * 64;
    const int p0 = rb * 8;                // 8 points per block (same batch: 8 | 2048)
    const int b = p0 >> 11;
    const float* xb = x + (size_t)b * NPT * ld;

    if (tid < 80) sidx[tid] = idx[p0 * KNN + tid];
    __syncthreads();

    for (int i = tid; i < 80 * C4; i += 256) {
        int r = i / C4, c4 = i - r * C4;
        float4 v = make_float4(0.f, 0.f, 0.f, 0.f);
        if (c4 * 4 < C) v = *(const float4*)(xb + (size_t)sidx[r] * ld + c4 * 4);
        As[r * C4 + (c4 ^ swz(r))] = v;
    }
    for (int i = tid; i < 64 * C4; i += 256) {
        int oo = i / C4, c4 = i - oo * C4;
        float4 v = make_float4(0.f, 0.f, 0.f, 0.f);
        if (c4 * 4 < C) v = *(const float4*)(W + (size_t)(o0 + oo) * 2 * C + c4 * 4);
        Bs[oo * C4 + (c4 ^ swz(oo))] = v;
    }
    __syncthreads();

    const int tx = tid & 15, ty = tid >> 4;
    const int o_l = tx * 4;
    float acc[5][4];
#pragma unroll
    for (int a = 0; a < 5; ++a)
#pragma unroll
        for (int c = 0; c < 4; ++c) acc[a][c] = 0.f;

    for (int c4 = 0; c4 < C4; ++c4) {
        float4 av[5], bv[4];
#pragma unroll
        for (int rj = 0; rj < 5; ++rj) { int r = ty * 5 + rj; av[rj] = As[r * C4 + (c4 ^ swz(r))]; }
#pragma unroll
        for (int oj = 0; oj < 4; ++oj) { int oo = o_l + oj; bv[oj] = Bs[oo * C4 + (c4 ^ swz(oo))]; }
#pragma unroll
        for (int rj = 0; rj < 5; ++rj)
#pragma unroll
            for (int oj = 0; oj < 4; ++oj) {
                acc[rj][oj] = fmaf(av[rj].x, bv[oj].x, acc[rj][oj]);
                acc[rj][oj] = fmaf(av[rj].y, bv[oj].y, acc[rj][oj]);
                acc[rj][oj] = fmaf(av[rj].z, bv[oj].z, acc[rj][oj]);
                acc[rj][oj] = fmaf(av[rj].w, bv[oj].w, acc[rj][oj]);
            }
    }

    // rows ty*5..ty*5+4 all belong to point pt = ty>>1 (k 0-4 for even ty, 5-9 odd)
    const int pt = ty >> 1;
    const float4 s4 = *(const float4*)(sbuf + (size_t)(p0 + pt) * O + o0 + o_l);
    const float* s4f = (const float*)&s4;

    if (PASS == 0) {
        double sum[4] = {0, 0, 0, 0}, sq[4] = {0, 0, 0, 0};
#pragma unroll
        for (int rj = 0; rj < 5; ++rj)
#pragma unroll
            for (int oj = 0; oj < 4; ++oj) {
                float hf = acc[rj][oj] + s4f[oj];
                double hd = (double)hf;
                sum[oj] += hd; sq[oj] += hd * hd;
            }
        __syncthreads();
        double* red = (double*)smem;   // [16][64][2] = 16 KB
#pragma unroll
        for (int oj = 0; oj < 4; ++oj) {
            red[(ty * 64 + o_l + oj) * 2 + 0] = sum[oj];
            red[(ty * 64 + o_l + oj) * 2 + 1] = sq[oj];
        }
        __syncthreads();
        if (tid < 128) {
            int o = tid & 63, w = tid >> 6;
            double a = 0.0;
            for (int t2 = 0; t2 < 16; ++t2) a += red[(t2 * 64 + o) * 2 + w];
            partials[(size_t)rb * 2 * O + (size_t)w * O + o0 + o] = a;
        }
    } else {
        float m4[4];
#pragma unroll
        for (int oj = 0; oj < 4; ++oj) {
            float sc = ss[o0 + o_l + oj], sh = ss[O + o0 + o_l + oj];
            float m = -FLT_MAX;
#pragma unroll
            for (int rj = 0; rj < 5; ++rj) {
                float h = (acc[rj][oj] + s4f[oj]) * sc + sh;
                h = h > 0.f ? h : 0.2f * h;
                m = fmaxf(m, h);
            }
            m4[oj] = m;
        }
        __syncthreads();
        float* red = smem;             // [16][64]
#pragma unroll
        for (int oj = 0; oj < 4; ++oj) red[ty * 64 + o_l + oj] = m4[oj];
        __syncthreads();
        if ((ty & 1) == 0) {
            float4 o4;
            float* po = (float*)&o4;
#pragma unroll
            for (int oj = 0; oj < 4; ++oj)
                po[oj] = fmaxf(red[ty * 64 + o_l + oj], red[(ty + 1) * 64 + o_l + oj]);
            *(float4*)(out + (size_t)(p0 + pt) * ldo + o0 + o_l) = o4;
        }
    }
}

// ---------------- BN finalize: deterministic fixed-order reduction ----------------
__global__ __launch_bounds__(256) void k_bnstats(const double* __restrict__ partials,
                                                 const float* __restrict__ g,
                                                 const float* __restrict__ be,
                                                 float* __restrict__ ss, int O) {
    int o = threadIdx.x;
    if (o >= O) return;
    double sum = 0.0, sq = 0.0;
    for (int b = 0; b < STAT_BLOCKS; ++b) {
        sum += partials[(size_t)b * 2 * O + o];
        sq  += partials[(size_t)b * 2 * O + O + o];
    }
    const double M = 163840.0;   // 8*2048*10
    double mu = sum / M;
    double var = sq / M - mu * mu;
    if (var < 0.0) var = 0.0;
    float scv = (float)((double)g[o] / sqrt(var + 1e-5));
    ss[o] = scv;
    ss[O + o] = be[o] - (float)mu * scv;
}

// ---------------- dense GEMM: 64x64 tile, BK=64, 4x4 acc/thread ----------------
template<int ACT>
__global__ __launch_bounds__(256, 2) void k_dense2(const float* __restrict__ in, int ldi, int Cin,
                                                   const float* __restrict__ W,
                                                   const float* __restrict__ bias,
                                                   float* __restrict__ out, int ldo, int Cout) {
    __shared__ __align__(16) float smem[2 * 64 * 64];   // As + Bs, 32 KB
    float4* As = (float4*)smem;
    float4* Bs = (float4*)(smem + 64 * 64);
    const int tid = threadIdx.x;
    const int p0 = blockIdx.x * 64;
    const int o0 = blockIdx.y * 64;
    const int tx = tid & 15, ty = tid >> 4;

    float acc[4][4];
#pragma unroll
    for (int a = 0; a < 4; ++a)
#pragma unroll
        for (int b = 0; b < 4; ++b) acc[a][b] = 0.f;

    const int ntile = (Cin + 63) / 64;
    for (int kt = 0; kt < ntile; ++kt) {
        const int c0 = kt * 64;
        __syncthreads();   // protect previous tile reads
        for (int i = tid; i < 64 * 16; i += 256) {
            int r = i >> 4, c4 = i & 15;
            float4 v = make_float4(0.f, 0.f, 0.f, 0.f);
            if (c0 + c4 * 4 < Cin) v = *(const float4*)(in + (size_t)(p0 + r) * ldi + c0 + c4 * 4);
            As[r * 16 + (c4 ^ swz(r))] = v;
        }
        for (int i = tid; i < 64 * 16; i += 256) {
            int oo = i >> 4, c4 = i & 15;
            float4 v = make_float4(0.f, 0.f, 0.f, 0.f);
            if (o0 + oo < Cout && c0 + c4 * 4 < Cin)
                v = *(const float4*)(W + (size_t)(o0 + oo) * Cin + c0 + c4 * 4);
            Bs[oo * 16 + (c4 ^ swz(oo))] = v;
        }
        __syncthreads();
#pragma unroll
        for (int c4 = 0; c4 < 16; ++c4) {
            float4 av[4], bv[4];
#pragma unroll
            for (int rj = 0; rj < 4; ++rj) { int r = ty * 4 + rj; av[rj] = As[r * 16 + (c4 ^ swz(r))]; }
#pragma unroll
            for (int oj = 0; oj < 4; ++oj) { int oo = tx * 4 + oj; bv[oj] = Bs[oo * 16 + (c4 ^ swz(oo))]; }
#pragma unroll
            for (int rj = 0; rj < 4; ++rj)
#pragma unroll
                for (int oj = 0; oj < 4; ++oj) {
                    acc[rj][oj] = fmaf(av[rj].x, bv[oj].x, acc[rj][oj]);
                    acc[rj][oj] = fmaf(av[rj].y, bv[oj].y, acc[rj][oj]);
                    acc[rj][oj] = fmaf(av[rj].z, bv[oj].z, acc[rj][oj]);
                    acc[rj][oj] = fmaf(av[rj].w, bv[oj].w, acc[rj][oj]);
                }
        }
    }

    const int ob = o0 + tx * 4;
    float bv4[4] = {0.f, 0.f, 0.f, 0.f};
    if (bias) {
#pragma unroll
        for (int oj = 0; oj < 4; ++oj) if (ob + oj < Cout) bv4[oj] = bias[ob + oj];
    }
#pragma unroll
    for (int rj = 0; rj < 4; ++rj) {
        float v4[4];
#pragma unroll
        for (int oj = 0; oj < 4; ++oj) {
            float v = acc[rj][oj] + bv4[oj];
            if (ACT) v = v > 0.f ? v : 0.2f * v;
            v4[oj] = v;
        }
        float* orow = out + (size_t)(p0 + ty * 4 + rj) * ldo;
        if (ob + 3 < Cout) {
            *(float4*)(orow + ob) = make_float4(v4[0], v4[1], v4[2], v4[3]);
        } else {
#pragma unroll
            for (int oj = 0; oj < 4; ++oj) if (ob + oj < Cout) orow[ob + oj] = v4[oj];
        }
    }
}

extern "C" void kernel_launch(void* const* d_in, const int* in_sizes, int n_in,
                              void* d_out, int out_size, void* d_ws, size_t ws_size,
                              hipStream_t stream) {
    const float* x   = (const float*)d_in[0];
    const float* W1  = (const float*)d_in[1];
    const float* g1  = (const float*)d_in[2];
    const float* b1  = (const float*)d_in[3];
    const float* W2  = (const float*)d_in[4];
    const float* g2  = (const float*)d_in[5];
    const float* b2  = (const float*)d_in[6];
    const float* W3  = (const float*)d_in[7];
    const float* g3  = (const float*)d_in[8];
    const float* b3  = (const float*)d_in[9];
    const float* W4  = (const float*)d_in[10];
    const float* g4  = (const float*)d_in[11];
    const float* b4  = (const float*)d_in[12];
    const float* W5  = (const float*)d_in[13];
    const float* W6  = (const float*)d_in[14];
    const float* Wd1 = (const float*)d_in[15];
    const float* bd1 = (const float*)d_in[16];
    const float* Wd2 = (const float*)d_in[17];
    const float* bd2 = (const float*)d_in[18];

    char* ws = (char*)d_ws;
    float* cat    = (float*)(ws);                 // [0, 33,554,432)
    double* norms = (double*)(ws + 33554432);     // 131,072 B (knn phase)
    float* qT     = (float*)(ws + 33685504);      // 8,388,608 B (knn phase)
    double* pk    = (double*)(ws + 42074112);     // 10,485,760 B (knn phase)
    int*   pi     = (int*)  (ws + 52559872);      // 5,242,880 B (knn phase)
    float* pts    = (float*)(ws + 57802752);      // 1,572,864 B (layer-1 input)
    int*   idx    = (int*)  (ws + 59375616);      // 655,360 B
    float* ssb    = (float*)(ws + 60030976);      // 4,096 B
    float* sbuf   = (float*)(ws + 33685504);      // <=16.8 MB, overlays qT+pk (conv phase)
    double* parts = (double*)(ws + 50462720);     // <=8.4 MB, overlays pk tail/pi/pts(L4 only)
    float* h5     = (float*)(ws + 33554432);      // tail only
    float* tmp    = (float*)(ws);                 // tail only, overlays dead cat

    float* feat = (float*)d_out;                // 16384 x 552
    float* logi = (float*)d_out + 9043968;      // 16384 x 255

    dim3 blk(256);
    dim3 kgrid(64, NCHUNK);   // x = query group (XCD-stable), y = chunk

    k_pts<<<dim3((NPTS_TOTAL * 24 + 255) / 256), blk, 0, stream>>>(x, pts);

    // ---- layer 1: C=24, O=64 ----
    k_prep<<<dim3(64), blk, 0, stream>>>(pts, 24, 24, norms, qT);
    k_knn2<24><<<kgrid, blk, 0, stream>>>(pts, 24, norms, qT, pk, pi);
    k_kmerge<<<dim3(64), blk, 0, stream>>>(pk, pi, idx);
    k_sgemm<24, 64><<<dim3(256, 1), blk, 0, stream>>>(pts, 24, W1, sbuf);
    k_conv2<0, 24, 64><<<dim3(STAT_BLOCKS, 1), blk, 0, stream>>>(pts, 24, idx, W1, sbuf, parts, nullptr, nullptr, 0);
    k_bnstats<<<dim3(1), blk, 0, stream>>>(parts, g1, b1, ssb, 64);
    k_conv2<1, 24, 64><<<dim3(STAT_BLOCKS, 1), blk, 0, stream>>>(pts, 24, idx, W1, sbuf, nullptr, ssb, cat + 0, 512);

    // ---- layer 2: C=64, O=64 ----
    k_prep<<<dim3(64), blk, 0, stream>>>(cat + 0, 512, 64, norms, qT);
    k_knn2<64><<<kgrid, blk, 0, stream>>>(cat + 0, 512, norms, qT, pk, pi);
    k_kmerge<<<dim3(64), blk, 0, stream>>>(pk, pi, idx);
    k_sgemm<64, 64><<<dim3(256, 1), blk, 0, stream>>>(cat + 0, 512, W2, sbuf);
    k_conv2<0, 64, 64><<<dim3(STAT_BLOCKS, 1), blk, 0, stream>>>(cat + 0, 512, idx, W2, sbuf, parts, nullptr, nullptr, 0);
    k_bnstats<<<dim3(1), blk, 0, stream>>>(parts, g2, b2, ssb, 64);
    k_conv2<1, 64, 64><<<dim3(STAT_BLOCKS, 1), blk, 0, stream>>>(cat + 0, 512, idx, W2, sbuf, nullptr, ssb, cat + 64, 512);

    // ---- layer 3: C=64, O=128 ----
    k_prep<<<dim3(64), blk, 0, stream>>>(cat + 64, 512, 64, norms, qT);
    k_knn2<64><<<kgrid, blk, 0, stream>>>(cat + 64, 512, norms, qT, pk, pi);
    k_kmerge<<<dim3(64), blk, 0, stream>>>(pk, pi, idx);
    k_sgemm<64, 128><<<dim3(256, 2), blk, 0, stream>>>(cat + 64, 512, W3, sbuf);
    k_conv2<0, 64, 128><<<dim3(STAT_BLOCKS, 2), blk, 0, stream>>>(cat + 64, 512, idx, W3, sbuf, parts, nullptr, nullptr, 0);
    k_bnstats<<<dim3(1), blk, 0, stream>>>(parts, g3, b3, ssb, 128);
    k_conv2<1, 64, 128><<<dim3(STAT_BLOCKS, 2), blk, 0, stream>>>(cat + 64, 512, idx, W3, sbuf, nullptr, ssb, cat + 128, 512);

    // ---- layer 4: C=128, O=256 ----
    k_prep<<<dim3(64), blk, 0, stream>>>(cat + 128, 512, 128, norms, qT);
    k_knn2<128><<<kgrid, blk, 0, stream>>>(cat + 128, 512, norms, qT, pk, pi);
    k_kmerge<<<dim3(64), blk, 0, stream>>>(pk, pi, idx);
    k_sgemm<128, 256><<<dim3(256, 4), blk, 0, stream>>>(cat + 128, 512, W4, sbuf);
    k_conv2<0, 128, 256><<<dim3(STAT_BLOCKS, 4), blk, 0, stream>>>(cat + 128, 512, idx, W4, sbuf, parts, nullptr, nullptr, 0);
    k_bnstats<<<dim3(1), blk, 0, stream>>>(parts, g4, b4, ssb, 256);
    k_conv2<1, 128, 256><<<dim3(STAT_BLOCKS, 4), blk, 0, stream>>>(cat + 128, 512, idx, W4, sbuf, nullptr, ssb, cat + 256, 512);

    // ---- tail: register-blocked GEMMs ----
    k_dense2<1><<<dim3(256, 4), blk, 0, stream>>>(cat, 512, 512, W5, nullptr, h5, 256, 256);
    k_dense2<1><<<dim3(256, 9), blk, 0, stream>>>(h5, 256, 256, W6, nullptr, feat, 552, 552);
    k_dense2<0><<<dim3(256, 9), blk, 0, stream>>>(feat, 552, 552, Wd1, bd1, tmp, 552, 552);
    k_dense2<0><<<dim3(256, 4), blk, 0, stream>>>(tmp, 552, 552, Wd2, bd2, logi, 255, 255);
}